// Round 25
// baseline (231.189 us; speedup 1.0000x reference)
//
#include <hip/hip_runtime.h>
#include <hip/hip_bf16.h>

typedef __attribute__((ext_vector_type(4))) float f32x4;
typedef __attribute__((ext_vector_type(8))) short bf16x8;
typedef unsigned int u32;
typedef unsigned short u16;

#define GASP __attribute__((address_space(1)))
#define LASP __attribute__((address_space(3)))

__device__ __forceinline__ u16 f2bf(float f) {
  u32 u = __float_as_uint(f);
  return (u16)((u + 0x7fffu + ((u >> 16) & 1u)) >> 16);
}

__device__ __forceinline__ u32 cvtpk(float lo, float hi) {
  u32 r;
  asm("v_cvt_pk_bf16_f32 %0, %1, %2" : "=v"(r) : "v"(lo), "v"(hi));
  return r;
}

__device__ __forceinline__ void gl_lds16(const void* g, void* l) {
  __builtin_amdgcn_global_load_lds((const GASP u32*)g, (LASP u32*)l, 16, 0, 0);
}

//============================ weight cast + transpose ============================
// W[K][N] fp32 -> Wt[N][K] bf16
struct CastArgs {
  const float* s[6];
  u16* d[6];
};

__global__ __launch_bounds__(256) void cast_w(CastArgs a) {
  int bid = blockIdx.x;
  int w, t, K, N, kshift;
  if (bid < 4096)      { w = bid >> 10; t = bid & 1023; K = 1024; N = 1024; kshift = 5; }
  else if (bid < 8192) { w = 4; t = bid - 4096; K = 1024; N = 4096; kshift = 5; }
  else                 { w = 5; t = bid - 8192; K = 4096; N = 1024; kshift = 7; }
  int tk = t & ((1 << kshift) - 1);
  int tn = t >> kshift;
  int k0 = tk << 5, n0 = tn << 5;
  const float* src = a.s[w];
  u16* dst = a.d[w];
  __shared__ u16 tile[32][36];
  int r = threadIdx.x >> 3, c0 = (threadIdx.x & 7) << 2;
  float4 v = *(const float4*)&src[(size_t)(k0 + r) * N + n0 + c0];
  tile[c0 + 0][r] = f2bf(v.x);
  tile[c0 + 1][r] = f2bf(v.y);
  tile[c0 + 2][r] = f2bf(v.z);
  tile[c0 + 3][r] = f2bf(v.w);
  __syncthreads();
  ushort4 o;
  o.x = tile[r][c0 + 0];
  o.y = tile[r][c0 + 1];
  o.z = tile[r][c0 + 2];
  o.w = tile[r][c0 + 3];
  *(ushort4*)&dst[(size_t)(n0 + r) * K + k0 + c0] = o;
}

//============================ layernorm -> bf16 ============================
__global__ __launch_bounds__(256) void ln_k(const float* __restrict__ x, const float* __restrict__ g,
                                            const float* __restrict__ b, u16* __restrict__ out) {
  int row = blockIdx.x;
  int tid = threadIdx.x;
  float4 v = *(const float4*)&x[(size_t)row * 1024 + tid * 4];
  float s = v.x + v.y + v.z + v.w;
  float ss = v.x * v.x + v.y * v.y + v.z * v.z + v.w * v.w;
#pragma unroll
  for (int o = 32; o >= 1; o >>= 1) {
    s += __shfl_xor(s, o, 64);
    ss += __shfl_xor(ss, o, 64);
  }
  __shared__ float red[8];
  int wv = tid >> 6;
  if ((tid & 63) == 0) { red[wv] = s; red[wv + 4] = ss; }
  __syncthreads();
  s = red[0] + red[1] + red[2] + red[3];
  ss = red[4] + red[5] + red[6] + red[7];
  float mu = s * (1.0f / 1024.0f);
  float var = ss * (1.0f / 1024.0f) - mu * mu;
  float rstd = rsqrtf(var + 1e-5f);
  float4 gv = *(const float4*)&g[tid * 4];
  float4 bv = *(const float4*)&b[tid * 4];
  ushort4 o4;
  o4.x = f2bf((v.x - mu) * rstd * gv.x + bv.x);
  o4.y = f2bf((v.y - mu) * rstd * gv.y + bv.y);
  o4.z = f2bf((v.z - mu) * rstd * gv.z + bv.z);
  o4.w = f2bf((v.w - mu) * rstd * gv.w + bv.w);
  *(ushort4*)&out[(size_t)row * 1024 + tid * 4] = o4;
}

//============================ 256xBN GEMM, 1-barrier-per-tile ============================
// (unchanged from R24 — validated)
template <int MODE, int BN>
__global__ __launch_bounds__(512, 2) void gemm_256(
    const u16* __restrict__ A, const u16* __restrict__ Bt,
    const float* __restrict__ bias0, const float* __restrict__ bias1, const float* __restrict__ bias2,
    void* outp, int rm, int rn, int xn, int M, int N, int K) {
  constexpr int NN = BN / 64;   // B fragments per wave (3 or 4)
  constexpr int BB = BN * 128;  // B dbuf bytes
  __shared__ __align__(16) u16 As[2][256 * 64];
  __shared__ __align__(16) u16 Bs[2][BN * 64];
  char* asB = (char*)As;
  char* bsB = (char*)Bs;
  const int tid = threadIdx.x;
  const int w = tid >> 6, lane = tid & 63;
  const int xcd = blockIdx.x & 7, idx = blockIdx.x >> 3;
  const int mt = (xcd / xn) * rm + (idx % rm);
  const int nt = (xcd % xn) * rn + (idx / rm);
  const int m0 = mt << 8, n0 = nt * BN;

  const int rA = tid >> 3;                       // row within 64-row pass
  const int csw = ((tid & 7) ^ (rA & 7)) * 8;    // pre-swizzled source chunk
  const u16* pA = A + (size_t)(m0 + rA) * K + csw;
  const u16* pB = Bt + (size_t)(n0 + rA) * K + csw;
  const int dstOff = tid * 16;

#define STG_A(kt, j) gl_lds16(pA + (size_t)((j) * 64) * K + (size_t)(kt) * 64, asB + aNB + (j) * 8192 + dstOff)
#define STG_B(kt, j) gl_lds16(pB + (size_t)((j) * 64) * K + (size_t)(kt) * 64, bsB + bNB + (j) * 8192 + dstOff)

  const int wr = w >> 2, wc = w & 3;
  const int g = lane >> 4, qi = lane & 15;

  int aOff[8][2], bOff[NN][2];
#pragma unroll
  for (int mm = 0; mm < 8; ++mm) {
    int row = wr * 128 + mm * 16 + qi;
#pragma unroll
    for (int ks = 0; ks < 2; ++ks)
      aOff[mm][ks] = row * 128 + (((ks * 4 + g) ^ (qi & 7)) << 4);
  }
#pragma unroll
  for (int nn = 0; nn < NN; ++nn) {
    int rowb = wc * (BN / 4) + nn * 16 + qi;
#pragma unroll
    for (int ks = 0; ks < 2; ++ks)
      bOff[nn][ks] = rowb * 128 + (((ks * 4 + g) ^ (qi & 7)) << 4);
  }

  f32x4 acc[8][NN];
#pragma unroll
  for (int i = 0; i < 8; ++i)
#pragma unroll
    for (int j = 0; j < NN; ++j) acc[i][j] = f32x4{0.f, 0.f, 0.f, 0.f};

#define PAIR(MB, A00, A01, A10, A11) do {                                                \
    __builtin_amdgcn_s_setprio(1);                                                       \
    _Pragma("unroll")                                                                    \
    for (int nn = 0; nn < NN; ++nn) {                                                    \
      acc[(MB)][nn] = __builtin_amdgcn_mfma_f32_16x16x32_bf16(A00, bv[nn][0], acc[(MB)][nn], 0, 0, 0);         \
      acc[(MB) + 1][nn] = __builtin_amdgcn_mfma_f32_16x16x32_bf16(A10, bv[nn][0], acc[(MB) + 1][nn], 0, 0, 0); \
    }                                                                                    \
    _Pragma("unroll")                                                                    \
    for (int nn = 0; nn < NN; ++nn) {                                                    \
      acc[(MB)][nn] = __builtin_amdgcn_mfma_f32_16x16x32_bf16(A01, bv[nn][1], acc[(MB)][nn], 0, 0, 0);         \
      acc[(MB) + 1][nn] = __builtin_amdgcn_mfma_f32_16x16x32_bf16(A11, bv[nn][1], acc[(MB) + 1][nn], 0, 0, 0); \
    }                                                                                    \
    __builtin_amdgcn_s_setprio(0);                                                       \
  } while (0)

#define RDA(dst0, dst1, MB)                                          \
    bf16x8 dst0##0 = *(const bf16x8*)(asB + aTB + aOff[(MB)][0]);     \
    bf16x8 dst0##1 = *(const bf16x8*)(asB + aTB + aOff[(MB)][1]);     \
    bf16x8 dst1##0 = *(const bf16x8*)(asB + aTB + aOff[(MB) + 1][0]); \
    bf16x8 dst1##1 = *(const bf16x8*)(asB + aTB + aOff[(MB) + 1][1]);

  const int T = K >> 6;
  // prologue: stage tile 0 into dbuf 0
#pragma unroll
  for (int j = 0; j < 4; ++j) gl_lds16(pA + (size_t)(j * 64) * K, asB + j * 8192 + dstOff);
#pragma unroll
  for (int j = 0; j < NN; ++j) gl_lds16(pB + (size_t)(j * 64) * K, bsB + j * 8192 + dstOff);
  asm volatile("s_waitcnt vmcnt(0)" ::: "memory");
  __builtin_amdgcn_s_barrier();

  for (int t = 0; t < T; ++t) {
    const int d = t & 1;
    const int aTB = d * 32768, bTB = d * BB;
    const int aNB = (d ^ 1) * 32768, bNB = (d ^ 1) * BB;
    const bool more = (t + 1 < T);
    const int kt1 = t + 1;
    bf16x8 bv[NN][2];
#pragma unroll
    for (int nn = 0; nn < NN; ++nn) {
      bv[nn][0] = *(const bf16x8*)(bsB + bTB + bOff[nn][0]);
      bv[nn][1] = *(const bf16x8*)(bsB + bTB + bOff[nn][1]);
    }
    RDA(p0a, p0b, 0);
    if (more) { STG_A(kt1, 0); STG_A(kt1, 1); }
    PAIR(0, p0a0, p0a1, p0b0, p0b1);
    RDA(p1a, p1b, 2);
    if (more) { STG_A(kt1, 2); STG_A(kt1, 3); }
    PAIR(2, p1a0, p1a1, p1b0, p1b1);
    RDA(p2a, p2b, 4);
    if (more) { STG_B(kt1, 0); STG_B(kt1, 1); }
    PAIR(4, p2a0, p2a1, p2b0, p2b1);
    RDA(p3a, p3b, 6);
    if (more) {
#pragma unroll
      for (int j = 2; j < NN; ++j) STG_B(kt1, j);
    }
    PAIR(6, p3a0, p3a1, p3b0, p3b1);
    asm volatile("" ::: "memory");
    if (more) { asm volatile("s_waitcnt vmcnt(0)" ::: "memory"); }
    __builtin_amdgcn_s_barrier();
  }
#undef PAIR
#undef RDA
#undef STG_A
#undef STG_B

  const int ci = lane & 15;
#pragma unroll
  for (int mm = 0; mm < 8; ++mm) {
#pragma unroll
    for (int nn = 0; nn < NN; ++nn) {
      int colb = n0 + wc * (BN / 4) + nn * 16 + ci;
      int rowbase = m0 + wr * 128 + mm * 16 + 4 * g;
      f32x4 c = acc[mm][nn];
      if constexpr (MODE == 2) {
        int sel = colb >> 10;
        int cc = colb & 1023;
        const float* bp = sel == 0 ? bias0 : (sel == 1 ? bias1 : bias2);
        float bb = bp[cc];
        int h = cc >> 6, dd = cc & 63;
        int b_ = rowbase >> 11, tt = rowbase & 2047;
        if (sel == 2) {
          // V^T: [B,H,64,T]; 4 consecutive t per lane -> vector store
          u16* op = (u16*)outp + 2ull * (4096ull * 1024ull);
          ushort4 o4;
          o4.x = f2bf(c[0] + bb);
          o4.y = f2bf(c[1] + bb);
          o4.z = f2bf(c[2] + bb);
          o4.w = f2bf(c[3] + bb);
          *(ushort4*)&op[((size_t)(b_ * 16 + h) * 64 + dd) * 2048 + tt] = o4;
        } else {
          float scale = (sel == 0) ? 0.125f : 1.0f;
          u16* op = (u16*)outp + (size_t)sel * (4096ull * 1024ull);
#pragma unroll
          for (int r = 0; r < 4; ++r)
            op[((size_t)(b_ * 16 + h) * 2048 + tt + r) * 64 + dd] = f2bf((c[r] + bb) * scale);
        }
      } else {  // MODE 3: gelu -> bf16
        float bb = bias0[colb];
#pragma unroll
        for (int r = 0; r < 4; ++r) {
          float v = c[r] + bb;
          float gl = 0.5f * v * (1.0f + erff(v * 0.70710678118654752f));
          ((u16*)outp)[(size_t)(rowbase + r) * N + colb] = f2bf(gl);
        }
      }
    }
  }
}

//============================ split-K GEMM (8 waves, 2 K-groups, PAIRED: 2 tiles/barrier) ============================
// 4 bufs as 2 pairs. Iteration s: compute tiles 2s,2s+1 from pair p=s&1 while
// staging tiles 2s+2,2s+3 into pair p^1 (disjoint); ONE vmcnt(0)+barrier per
// 2 tiles (32 MFMA/wave between barriers — same ledger as the attn pairing).
// T = K/64 is always even (16 for Wo, 64 for W2).
__global__ __launch_bounds__(512) void gemm_sk(
    const u16* __restrict__ A, const u16* __restrict__ Bt,
    const float* __restrict__ bias0, float* __restrict__ outp,
    const float* __restrict__ res, int M, int N, int K) {
  __shared__ __align__(16) union SM {
    struct { u16 As[2][4][128 * 32]; u16 Bs[2][4][128 * 32]; } t;  // [grp][buf]
    float red[16][4][4][64];
  } sm;
  const int tid = threadIdx.x;
  const int w8 = tid >> 6, lane = tid & 63;
  const int gg = w8 >> 2, wl = w8 & 3;
  const int m0 = blockIdx.y << 7, n0 = blockIdx.x << 7;

  char* asB = (char*)sm.t.As[gg];
  char* bsB = (char*)sm.t.Bs[gg];
  const u16* aS[2];
  const u16* bS[2];
#pragma unroll
  for (int i = 0; i < 2; ++i) {
    int p = wl * 2048 + i * 1024 + lane * 16;
    int r = p >> 6;
    int cl = ((p >> 4) & 3) ^ ((r >> 1) & 3);
    aS[i] = A + (size_t)(m0 + r) * K + gg * 32 + cl * 8;
    bS[i] = Bt + (size_t)(n0 + r) * K + gg * 32 + cl * 8;
  }
  f32x4 acc[4][4];
#pragma unroll
  for (int i = 0; i < 4; ++i)
#pragma unroll
    for (int j = 0; j < 4; ++j) acc[i][j] = f32x4{0.f, 0.f, 0.f, 0.f};

  const int wr = wl >> 1, wc = wl & 1;
  int aOff[4], bOff[4];
#pragma unroll
  for (int mm = 0; mm < 4; ++mm) {
    int rowa = wr * 64 + mm * 16 + (lane & 15);
    aOff[mm] = rowa * 64 + (((lane >> 4) ^ ((rowa >> 1) & 3)) << 4);
    int rowb = wc * 64 + mm * 16 + (lane & 15);
    bOff[mm] = rowb * 64 + (((lane >> 4) ^ ((rowb >> 1) & 3)) << 4);
  }

#define SK_STG(kt, b) do {                                          \
    const size_t ko = (size_t)(kt) * 64;                            \
    gl_lds16(aS[0] + ko, asB + (b) * 8192 + wl * 2048);             \
    gl_lds16(aS[1] + ko, asB + (b) * 8192 + wl * 2048 + 1024);      \
    gl_lds16(bS[0] + ko, bsB + (b) * 8192 + wl * 2048);             \
    gl_lds16(bS[1] + ko, bsB + (b) * 8192 + wl * 2048 + 1024);      \
  } while (0)

#define SK_CMP(b) do {                                              \
    const int tb = (b) * 8192;                                      \
    bf16x8 av[4], bv[4];                                            \
    _Pragma("unroll")                                               \
    for (int mm = 0; mm < 4; ++mm) av[mm] = *(const bf16x8*)(asB + tb + aOff[mm]); \
    _Pragma("unroll")                                               \
    for (int nn = 0; nn < 4; ++nn) bv[nn] = *(const bf16x8*)(bsB + tb + bOff[nn]); \
    __builtin_amdgcn_s_setprio(1);                                  \
    _Pragma("unroll")                                               \
    for (int mm = 0; mm < 4; ++mm)                                  \
      _Pragma("unroll")                                             \
      for (int nn = 0; nn < 4; ++nn)                                \
        acc[mm][nn] = __builtin_amdgcn_mfma_f32_16x16x32_bf16(av[mm], bv[nn], acc[mm][nn], 0, 0, 0); \
    __builtin_amdgcn_s_setprio(0);                                  \
  } while (0)

  // prologue: stage tiles 0,1 into bufs 0,1
  SK_STG(0, 0);
  SK_STG(1, 1);
  asm volatile("s_waitcnt vmcnt(0)" ::: "memory");
  __builtin_amdgcn_s_barrier();

  const int T = K >> 6;           // always even (16 or 64)
  const int iters = T >> 1;
  for (int s = 0; s < iters; ++s) {
    const int p = s & 1;
    const int rb = p * 2;         // read bufs rb, rb+1 (tiles 2s, 2s+1)
    const int sb = (p ^ 1) * 2;   // stage bufs (tiles 2s+2, 2s+3)
    const bool more = (s + 1 < iters);
    if (more) {
      SK_STG(2 * s + 2, sb);
      SK_STG(2 * s + 3, sb + 1);
    }
    SK_CMP(rb);
    SK_CMP(rb + 1);
    asm volatile("" ::: "memory");
    if (more) { asm volatile("s_waitcnt vmcnt(0)" ::: "memory"); }
    __builtin_amdgcn_s_barrier();
  }
#undef SK_STG
#undef SK_CMP

  __syncthreads();  // all tile reads done before red overwrites the union
  if (gg == 1) {
#pragma unroll
    for (int mm = 0; mm < 4; ++mm)
#pragma unroll
      for (int nn = 0; nn < 4; ++nn)
#pragma unroll
        for (int r = 0; r < 4; ++r) sm.red[mm * 4 + nn][r][wl][lane] = acc[mm][nn][r];
  }
  __syncthreads();
  if (gg == 0) {
    const int g = lane >> 4, ci = lane & 15;
#pragma unroll
    for (int mm = 0; mm < 4; ++mm) {
#pragma unroll
      for (int nn = 0; nn < 4; ++nn) {
        int colb = n0 + wc * 64 + nn * 16 + ci;
        int rowbase = m0 + wr * 64 + mm * 16 + 4 * g;
        float bb = bias0[colb];
#pragma unroll
        for (int r = 0; r < 4; ++r) {
          size_t idx = (size_t)(rowbase + r) * N + colb;
          outp[idx] = acc[mm][nn][r] + sm.red[mm * 4 + nn][r][wl][lane] + bb + res[idx];
        }
      }
    }
  }
}

//============================ flash attention (8x16 paired, 4 steps/barrier) ============================
// (unchanged from R24 — validated)
__global__ __launch_bounds__(512) void attn_k(const u16* __restrict__ Q, const u16* __restrict__ Kg,
                                              const u16* __restrict__ Vt, u16* __restrict__ O) {
  __shared__ __align__(16) u16 Ks[2][4][64 * 64];  // [phase][step]
  __shared__ __align__(16) u16 Vs[2][4][64 * 64];
  const int bx = blockIdx.y;  // 0..7
  const int bh = blockIdx.x;  // 0..31
  const int tid = threadIdx.x, w = tid >> 6, lane = tid & 63;
  const int g = lane >> 4, qi = lane & 15;
  const u16* Qb = Q + (size_t)bh * 2048 * 64;
  const u16* Kb = Kg + (size_t)bh * 2048 * 64;
  const u16* Vtb = Vt + (size_t)bh * 64 * 2048;

  const int rS = tid >> 3, cS = tid & 7;
  const int csw = (cS ^ (rS & 7)) * 8;
  const u16* srcK = Kb + (size_t)rS * 64 + csw;
  const u16* srcV = Vtb + (size_t)rS * 2048 + csw;
  char* ksB = (char*)Ks;
  char* vsB = (char*)Vs;
  const int dstOff = tid * 16;

  int koff[4][2], voff[4][2];
#pragma unroll
  for (int t = 0; t < 4; ++t) {
    int row = 16 * t + qi;
#pragma unroll
    for (int h = 0; h < 2; ++h) koff[t][h] = row * 128 + (((4 * h + g) ^ (qi & 7)) << 4);
#pragma unroll
    for (int kt = 0; kt < 2; ++kt) voff[t][kt] = row * 128 + (((4 * kt + g) ^ (qi & 7)) << 4);
  }

  const int b_ = bh >> 4, hh = bh & 15;
  u32* Ou = (u32*)O;

  for (int job = 0; job < 2; ++job) {
    const int qt = job ? bx : 15 - bx;
    const int qmin = qt * 128 + w * 16;
    const int qrow = qmin + qi;
    const int qmaxw = qmin + 15;

    bf16x8 qf[2];
#pragma unroll
    for (int h = 0; h < 2; ++h)
      qf[h] = *(const bf16x8*)(Qb + (size_t)qrow * 64 + h * 32 + g * 8);

    f32x4 acc[4];
#pragma unroll
    for (int dt = 0; dt < 4; ++dt) acc[dt] = f32x4{0.f, 0.f, 0.f, 0.f};
    float m = -1e30f, lsum = 0.0f;

    __syncthreads();  // protect LDS reuse across jobs
#pragma unroll
    for (int j = 0; j < 4; ++j) {
      gl_lds16(srcK + (size_t)j * 4096, ksB + j * 8192 + dstOff);
      gl_lds16(srcV + (size_t)j * 64, vsB + j * 8192 + dstOff);
    }

    const int nsteps = 2 * qt + 2;
    const int quads = (nsteps + 3) >> 2;
    int ph = 0;
    for (int ss = 0; ss < quads; ++ss) {
      __syncthreads();
      if (ss + 1 < quads) {
        const int nb = (ph ^ 1) * 32768;
#pragma unroll
        for (int j = 0; j < 4; ++j) {
          const int sj = 4 * ss + 4 + j;
          gl_lds16(srcK + (size_t)sj * 4096, ksB + nb + j * 8192 + dstOff);
          gl_lds16(srcV + (size_t)sj * 64, vsB + nb + j * 8192 + dstOff);
        }
      }
#pragma unroll
      for (int j = 0; j < 4; ++j) {
        const int s = 4 * ss + j;
        const int kv0 = s * 64;
        if (kv0 <= qmaxw) {
          const int tb = ph * 32768 + j * 8192;
          f32x4 st[4];
          __builtin_amdgcn_s_setprio(1);
#pragma unroll
          for (int t = 0; t < 4; ++t) {
            st[t] = f32x4{0.f, 0.f, 0.f, 0.f};
#pragma unroll
            for (int h = 0; h < 2; ++h) {
              bf16x8 kf = *(const bf16x8*)(ksB + tb + koff[t][h]);
              st[t] = __builtin_amdgcn_mfma_f32_16x16x32_bf16(kf, qf[h], st[t], 0, 0, 0);
            }
          }
          __builtin_amdgcn_s_setprio(0);
          float pvv[4][4];
          float tmax = -1e30f;
          if (kv0 + 63 > qmin) {
#pragma unroll
            for (int t = 0; t < 4; ++t)
#pragma unroll
              for (int r = 0; r < 4; ++r) {
                int key = kv0 + 16 * t + 4 * g + r;
                float sv = st[t][r];
                sv = (key <= qrow) ? sv : -1e30f;
                pvv[t][r] = sv;
                tmax = fmaxf(tmax, sv);
              }
          } else {
#pragma unroll
            for (int t = 0; t < 4; ++t)
#pragma unroll
              for (int r = 0; r < 4; ++r) {
                float sv = st[t][r];
                pvv[t][r] = sv;
                tmax = fmaxf(tmax, sv);
              }
          }
          tmax = fmaxf(tmax, __shfl_xor(tmax, 16, 64));
          tmax = fmaxf(tmax, __shfl_xor(tmax, 32, 64));
          if (!__all(tmax <= m + 8.0f)) {  // defer-max (T13)
            float mn = fmaxf(m, tmax);
            float corr = __expf(m - mn);
            lsum *= corr;
#pragma unroll
            for (int dt = 0; dt < 4; ++dt)
#pragma unroll
              for (int r = 0; r < 4; ++r) acc[dt][r] *= corr;
            m = mn;
          }
          float tsum = 0.f;
#pragma unroll
          for (int t = 0; t < 4; ++t)
#pragma unroll
            for (int r = 0; r < 4; ++r) {
              float e = __expf(pvv[t][r] - m);
              pvv[t][r] = e;
              tsum += e;
            }
          tsum += __shfl_xor(tsum, 16, 64);
          tsum += __shfl_xor(tsum, 32, 64);
          lsum += tsum;
          u32 pk[4][2], ex[4][2];
#pragma unroll
          for (int t = 0; t < 4; ++t)
#pragma unroll
            for (int p = 0; p < 2; ++p) {
              u32 v = cvtpk(pvv[t][2 * p], pvv[t][2 * p + 1]);
              pk[t][p] = v;
              ex[t][p] = (u32)__shfl_xor((int)v, 16, 64);
            }
          const bool ge = (g & 1) == 0;
          const bool G0 = (g >> 1) == 0;
          const bool innr = (g == 0) || (g == 3);
          u32 mm_[4][4];
#pragma unroll
          for (int t = 0; t < 4; ++t) {
            mm_[t][0] = ge ? pk[t][0] : ex[t][0];
            mm_[t][1] = ge ? pk[t][1] : ex[t][1];
            mm_[t][2] = ge ? ex[t][0] : pk[t][0];
            mm_[t][3] = ge ? ex[t][1] : pk[t][1];
          }
          union Frag { u32 u[4]; bf16x8 v; } f0, f1;
#pragma unroll
          for (int i = 0; i < 4; ++i) {
            u32 sel0 = G0 ? mm_[1][i] : mm_[0][i];
            u32 sel1 = G0 ? mm_[3][i] : mm_[2][i];
            u32 sw0 = (u32)__shfl_xor((int)sel0, 32, 64);
            u32 sw1 = (u32)__shfl_xor((int)sel1, 32, 64);
            u32 own0 = G0 ? mm_[0][i] : mm_[1][i];
            u32 own1 = G0 ? mm_[2][i] : mm_[3][i];
            f0.u[i] = innr ? own0 : sw0;
            f1.u[i] = innr ? own1 : sw1;
          }
          __builtin_amdgcn_s_setprio(1);
#pragma unroll
          for (int dt = 0; dt < 4; ++dt) {
            bf16x8 vfa = *(const bf16x8*)(vsB + tb + voff[dt][0]);
            acc[dt] = __builtin_amdgcn_mfma_f32_16x16x32_bf16(vfa, f0.v, acc[dt], 0, 0, 0);
            bf16x8 vfb = *(const bf16x8*)(vsB + tb + voff[dt][1]);
            acc[dt] = __builtin_amdgcn_mfma_f32_16x16x32_bf16(vfb, f1.v, acc[dt], 0, 0, 0);
          }
          __builtin_amdgcn_s_setprio(0);
        }
      }
      ph ^= 1;
    }

    float rl = 1.0f / lsum;
    size_t rowq = (size_t)(b_ * 2048 + qrow);
#pragma unroll
    for (int dt = 0; dt < 4; ++dt) {
#pragma unroll
      for (int rp = 0; rp < 2; ++rp) {
        u16 lo = f2bf(acc[dt][rp * 2] * rl);
        u16 hi = f2bf(acc[dt][rp * 2 + 1] * rl);
        u32 pkd = (u32)lo | ((u32)hi << 16);
        size_t off = rowq * 1024 + hh * 64 + dt * 16 + 4 * g + rp * 2;
        Ou[off >> 1] = pkd;
      }
    }
  }
}

//============================ launch ============================
extern "C" void kernel_launch(void* const* d_in, const int* in_sizes, int n_in,
                              void* d_out, int out_size, void* d_ws, size_t ws_size,
                              hipStream_t stream) {
  const float* x    = (const float*)d_in[0];
  const float* ln1g = (const float*)d_in[1];
  const float* ln1b = (const float*)d_in[2];
  const float* Wq   = (const float*)d_in[3];
  const float* bq   = (const float*)d_in[4];
  const float* Wk   = (const float*)d_in[5];
  const float* bk   = (const float*)d_in[6];
  const float* Wv   = (const float*)d_in[7];
  const float* bv   = (const float*)d_in[8];
  const float* Wo   = (const float*)d_in[9];
  const float* bo   = (const float*)d_in[10];
  const float* ln2g = (const float*)d_in[11];
  const float* ln2b = (const float*)d_in[12];
  const float* W1   = (const float*)d_in[13];
  const float* b1   = (const float*)d_in[14];
  const float* W2   = (const float*)d_in[15];
  const float* b2   = (const float*)d_in[16];

  char* ws = (char*)d_ws;
  const size_t MB = 1ull << 20;
  u16* WqT = (u16*)(ws + 0 * MB);   // [1024][1024]; WqT/WkT/WvT contiguous => [3072][1024]
  u16* WkT = (u16*)(ws + 2 * MB);   // [1024][1024]
  u16* WvT = (u16*)(ws + 4 * MB);   // [1024][1024]
  u16* WoT = (u16*)(ws + 6 * MB);   // [1024][1024]
  u16* W1T = (u16*)(ws + 8 * MB);   // [4096][1024]
  u16* W2T = (u16*)(ws + 16 * MB);  // [1024][4096]
  u16* XN  = (u16*)(ws + 24 * MB);  // [4096][1024] bf16 (ln1 out, later ln2 out)
  u16* Qb  = (u16*)(ws + 32 * MB);  // [B,H,T,64] bf16
  u16* Kb  = (u16*)(ws + 40 * MB);  // [B,H,T,64] bf16
  u16* Vtb = (u16*)(ws + 48 * MB);  // [B,H,64,T] bf16 (transposed)
  u16* Ob  = (u16*)(ws + 56 * MB);  // [4096][1024] bf16
  u16* Gb  = (u16*)(ws + 32 * MB);  // [4096][4096] bf16, aliases Q/K/V/O (dead by then)

  CastArgs ca;
  ca.s[0] = Wq; ca.s[1] = Wk; ca.s[2] = Wv; ca.s[3] = Wo; ca.s[4] = W1; ca.s[5] = W2;
  ca.d[0] = WqT; ca.d[1] = WkT; ca.d[2] = WvT; ca.d[3] = WoT; ca.d[4] = W1T; ca.d[5] = W2T;
  cast_w<<<12288, 256, 0, stream>>>(ca);

  ln_k<<<4096, 256, 0, stream>>>(x, ln1g, ln1b, XN);

  // fused QKV: [4096,1024] @ [1024,3072] — 256x192 tiles -> 16x16 grid = 256 blocks
  gemm_256<2, 192><<<256, 512, 0, stream>>>(XN, WqT, bq, bk, bv, Qb, 8, 4, 4, 4096, 3072, 1024);

  attn_k<<<dim3(32, 8), 512, 0, stream>>>(Qb, Kb, Vtb, Ob);

  // x1 = x + attn @ Wo + bo   (x1 lives in d_out) — split-K, paired
  gemm_sk<<<dim3(8, 32), 512, 0, stream>>>(Ob, WoT, bo, (float*)d_out, x, 4096, 1024, 1024);

  ln_k<<<4096, 256, 0, stream>>>((const float*)d_out, ln2g, ln2b, XN);

  // G = gelu(h @ W1 + b1) — 256x256 tiles; XCD region 8m x 4n
  gemm_256<3, 256><<<256, 512, 0, stream>>>(XN, W1T, b1, nullptr, nullptr, Gb, 8, 4, 4, 4096, 4096, 1024);

  // out = x1 + G @ W2 + b2  (in place over d_out) — split-K, paired
  gemm_sk<<<dim3(8, 32), 512, 0, stream>>>(Gb, W2T, b2, (float*)d_out, (const float*)d_out, 4096, 1024, 4096);
}

// Round 26
// 221.258 us; speedup vs baseline: 1.0449x; 1.0449x over previous
//
#include <hip/hip_runtime.h>
#include <hip/hip_bf16.h>

typedef __attribute__((ext_vector_type(4))) float f32x4;
typedef __attribute__((ext_vector_type(8))) short bf16x8;
typedef unsigned int u32;
typedef unsigned short u16;

#define GASP __attribute__((address_space(1)))
#define LASP __attribute__((address_space(3)))

__device__ __forceinline__ u16 f2bf(float f) {
  u32 u = __float_as_uint(f);
  return (u16)((u + 0x7fffu + ((u >> 16) & 1u)) >> 16);
}

__device__ __forceinline__ u32 cvtpk(float lo, float hi) {
  u32 r;
  asm("v_cvt_pk_bf16_f32 %0, %1, %2" : "=v"(r) : "v"(lo), "v"(hi));
  return r;
}

__device__ __forceinline__ void gl_lds16(const void* g, void* l) {
  __builtin_amdgcn_global_load_lds((const GASP u32*)g, (LASP u32*)l, 16, 0, 0);
}

//============================ weight cast + transpose ============================
// W[K][N] fp32 -> Wt[N][K] bf16
struct CastArgs {
  const float* s[6];
  u16* d[6];
};

__global__ __launch_bounds__(256) void cast_w(CastArgs a) {
  int bid = blockIdx.x;
  int w, t, K, N, kshift;
  if (bid < 4096)      { w = bid >> 10; t = bid & 1023; K = 1024; N = 1024; kshift = 5; }
  else if (bid < 8192) { w = 4; t = bid - 4096; K = 1024; N = 4096; kshift = 5; }
  else                 { w = 5; t = bid - 8192; K = 4096; N = 1024; kshift = 7; }
  int tk = t & ((1 << kshift) - 1);
  int tn = t >> kshift;
  int k0 = tk << 5, n0 = tn << 5;
  const float* src = a.s[w];
  u16* dst = a.d[w];
  __shared__ u16 tile[32][36];
  int r = threadIdx.x >> 3, c0 = (threadIdx.x & 7) << 2;
  float4 v = *(const float4*)&src[(size_t)(k0 + r) * N + n0 + c0];
  tile[c0 + 0][r] = f2bf(v.x);
  tile[c0 + 1][r] = f2bf(v.y);
  tile[c0 + 2][r] = f2bf(v.z);
  tile[c0 + 3][r] = f2bf(v.w);
  __syncthreads();
  ushort4 o;
  o.x = tile[r][c0 + 0];
  o.y = tile[r][c0 + 1];
  o.z = tile[r][c0 + 2];
  o.w = tile[r][c0 + 3];
  *(ushort4*)&dst[(size_t)(n0 + r) * K + k0 + c0] = o;
}

//============================ layernorm -> bf16 ============================
__global__ __launch_bounds__(256) void ln_k(const float* __restrict__ x, const float* __restrict__ g,
                                            const float* __restrict__ b, u16* __restrict__ out) {
  int row = blockIdx.x;
  int tid = threadIdx.x;
  float4 v = *(const float4*)&x[(size_t)row * 1024 + tid * 4];
  float s = v.x + v.y + v.z + v.w;
  float ss = v.x * v.x + v.y * v.y + v.z * v.z + v.w * v.w;
#pragma unroll
  for (int o = 32; o >= 1; o >>= 1) {
    s += __shfl_xor(s, o, 64);
    ss += __shfl_xor(ss, o, 64);
  }
  __shared__ float red[8];
  int wv = tid >> 6;
  if ((tid & 63) == 0) { red[wv] = s; red[wv + 4] = ss; }
  __syncthreads();
  s = red[0] + red[1] + red[2] + red[3];
  ss = red[4] + red[5] + red[6] + red[7];
  float mu = s * (1.0f / 1024.0f);
  float var = ss * (1.0f / 1024.0f) - mu * mu;
  float rstd = rsqrtf(var + 1e-5f);
  float4 gv = *(const float4*)&g[tid * 4];
  float4 bv = *(const float4*)&b[tid * 4];
  ushort4 o4;
  o4.x = f2bf((v.x - mu) * rstd * gv.x + bv.x);
  o4.y = f2bf((v.y - mu) * rstd * gv.y + bv.y);
  o4.z = f2bf((v.z - mu) * rstd * gv.z + bv.z);
  o4.w = f2bf((v.w - mu) * rstd * gv.w + bv.w);
  *(ushort4*)&out[(size_t)row * 1024 + tid * 4] = o4;
}

//============================ 256xBN GEMM, 1-barrier-per-tile ============================
// (unchanged from R24 — validated)
template <int MODE, int BN>
__global__ __launch_bounds__(512, 2) void gemm_256(
    const u16* __restrict__ A, const u16* __restrict__ Bt,
    const float* __restrict__ bias0, const float* __restrict__ bias1, const float* __restrict__ bias2,
    void* outp, int rm, int rn, int xn, int M, int N, int K) {
  constexpr int NN = BN / 64;   // B fragments per wave (3 or 4)
  constexpr int BB = BN * 128;  // B dbuf bytes
  __shared__ __align__(16) u16 As[2][256 * 64];
  __shared__ __align__(16) u16 Bs[2][BN * 64];
  char* asB = (char*)As;
  char* bsB = (char*)Bs;
  const int tid = threadIdx.x;
  const int w = tid >> 6, lane = tid & 63;
  const int xcd = blockIdx.x & 7, idx = blockIdx.x >> 3;
  const int mt = (xcd / xn) * rm + (idx % rm);
  const int nt = (xcd % xn) * rn + (idx / rm);
  const int m0 = mt << 8, n0 = nt * BN;

  const int rA = tid >> 3;                       // row within 64-row pass
  const int csw = ((tid & 7) ^ (rA & 7)) * 8;    // pre-swizzled source chunk
  const u16* pA = A + (size_t)(m0 + rA) * K + csw;
  const u16* pB = Bt + (size_t)(n0 + rA) * K + csw;
  const int dstOff = tid * 16;

#define STG_A(kt, j) gl_lds16(pA + (size_t)((j) * 64) * K + (size_t)(kt) * 64, asB + aNB + (j) * 8192 + dstOff)
#define STG_B(kt, j) gl_lds16(pB + (size_t)((j) * 64) * K + (size_t)(kt) * 64, bsB + bNB + (j) * 8192 + dstOff)

  const int wr = w >> 2, wc = w & 3;
  const int g = lane >> 4, qi = lane & 15;

  int aOff[8][2], bOff[NN][2];
#pragma unroll
  for (int mm = 0; mm < 8; ++mm) {
    int row = wr * 128 + mm * 16 + qi;
#pragma unroll
    for (int ks = 0; ks < 2; ++ks)
      aOff[mm][ks] = row * 128 + (((ks * 4 + g) ^ (qi & 7)) << 4);
  }
#pragma unroll
  for (int nn = 0; nn < NN; ++nn) {
    int rowb = wc * (BN / 4) + nn * 16 + qi;
#pragma unroll
    for (int ks = 0; ks < 2; ++ks)
      bOff[nn][ks] = rowb * 128 + (((ks * 4 + g) ^ (qi & 7)) << 4);
  }

  f32x4 acc[8][NN];
#pragma unroll
  for (int i = 0; i < 8; ++i)
#pragma unroll
    for (int j = 0; j < NN; ++j) acc[i][j] = f32x4{0.f, 0.f, 0.f, 0.f};

#define PAIR(MB, A00, A01, A10, A11) do {                                                \
    __builtin_amdgcn_s_setprio(1);                                                       \
    _Pragma("unroll")                                                                    \
    for (int nn = 0; nn < NN; ++nn) {                                                    \
      acc[(MB)][nn] = __builtin_amdgcn_mfma_f32_16x16x32_bf16(A00, bv[nn][0], acc[(MB)][nn], 0, 0, 0);         \
      acc[(MB) + 1][nn] = __builtin_amdgcn_mfma_f32_16x16x32_bf16(A10, bv[nn][0], acc[(MB) + 1][nn], 0, 0, 0); \
    }                                                                                    \
    _Pragma("unroll")                                                                    \
    for (int nn = 0; nn < NN; ++nn) {                                                    \
      acc[(MB)][nn] = __builtin_amdgcn_mfma_f32_16x16x32_bf16(A01, bv[nn][1], acc[(MB)][nn], 0, 0, 0);         \
      acc[(MB) + 1][nn] = __builtin_amdgcn_mfma_f32_16x16x32_bf16(A11, bv[nn][1], acc[(MB) + 1][nn], 0, 0, 0); \
    }                                                                                    \
    __builtin_amdgcn_s_setprio(0);                                                       \
  } while (0)

#define RDA(dst0, dst1, MB)                                          \
    bf16x8 dst0##0 = *(const bf16x8*)(asB + aTB + aOff[(MB)][0]);     \
    bf16x8 dst0##1 = *(const bf16x8*)(asB + aTB + aOff[(MB)][1]);     \
    bf16x8 dst1##0 = *(const bf16x8*)(asB + aTB + aOff[(MB) + 1][0]); \
    bf16x8 dst1##1 = *(const bf16x8*)(asB + aTB + aOff[(MB) + 1][1]);

  const int T = K >> 6;
  // prologue: stage tile 0 into dbuf 0
#pragma unroll
  for (int j = 0; j < 4; ++j) gl_lds16(pA + (size_t)(j * 64) * K, asB + j * 8192 + dstOff);
#pragma unroll
  for (int j = 0; j < NN; ++j) gl_lds16(pB + (size_t)(j * 64) * K, bsB + j * 8192 + dstOff);
  asm volatile("s_waitcnt vmcnt(0)" ::: "memory");
  __builtin_amdgcn_s_barrier();

  for (int t = 0; t < T; ++t) {
    const int d = t & 1;
    const int aTB = d * 32768, bTB = d * BB;
    const int aNB = (d ^ 1) * 32768, bNB = (d ^ 1) * BB;
    const bool more = (t + 1 < T);
    const int kt1 = t + 1;
    bf16x8 bv[NN][2];
#pragma unroll
    for (int nn = 0; nn < NN; ++nn) {
      bv[nn][0] = *(const bf16x8*)(bsB + bTB + bOff[nn][0]);
      bv[nn][1] = *(const bf16x8*)(bsB + bTB + bOff[nn][1]);
    }
    RDA(p0a, p0b, 0);
    if (more) { STG_A(kt1, 0); STG_A(kt1, 1); }
    PAIR(0, p0a0, p0a1, p0b0, p0b1);
    RDA(p1a, p1b, 2);
    if (more) { STG_A(kt1, 2); STG_A(kt1, 3); }
    PAIR(2, p1a0, p1a1, p1b0, p1b1);
    RDA(p2a, p2b, 4);
    if (more) { STG_B(kt1, 0); STG_B(kt1, 1); }
    PAIR(4, p2a0, p2a1, p2b0, p2b1);
    RDA(p3a, p3b, 6);
    if (more) {
#pragma unroll
      for (int j = 2; j < NN; ++j) STG_B(kt1, j);
    }
    PAIR(6, p3a0, p3a1, p3b0, p3b1);
    asm volatile("" ::: "memory");
    if (more) { asm volatile("s_waitcnt vmcnt(0)" ::: "memory"); }
    __builtin_amdgcn_s_barrier();
  }
#undef PAIR
#undef RDA
#undef STG_A
#undef STG_B

  const int ci = lane & 15;
#pragma unroll
  for (int mm = 0; mm < 8; ++mm) {
#pragma unroll
    for (int nn = 0; nn < NN; ++nn) {
      int colb = n0 + wc * (BN / 4) + nn * 16 + ci;
      int rowbase = m0 + wr * 128 + mm * 16 + 4 * g;
      f32x4 c = acc[mm][nn];
      if constexpr (MODE == 2) {
        int sel = colb >> 10;
        int cc = colb & 1023;
        const float* bp = sel == 0 ? bias0 : (sel == 1 ? bias1 : bias2);
        float bb = bp[cc];
        int h = cc >> 6, dd = cc & 63;
        int b_ = rowbase >> 11, tt = rowbase & 2047;
        if (sel == 2) {
          // V^T: [B,H,64,T]; 4 consecutive t per lane -> vector store
          u16* op = (u16*)outp + 2ull * (4096ull * 1024ull);
          ushort4 o4;
          o4.x = f2bf(c[0] + bb);
          o4.y = f2bf(c[1] + bb);
          o4.z = f2bf(c[2] + bb);
          o4.w = f2bf(c[3] + bb);
          *(ushort4*)&op[((size_t)(b_ * 16 + h) * 64 + dd) * 2048 + tt] = o4;
        } else {
          float scale = (sel == 0) ? 0.125f : 1.0f;
          u16* op = (u16*)outp + (size_t)sel * (4096ull * 1024ull);
#pragma unroll
          for (int r = 0; r < 4; ++r)
            op[((size_t)(b_ * 16 + h) * 2048 + tt + r) * 64 + dd] = f2bf((c[r] + bb) * scale);
        }
      } else {  // MODE 3: gelu -> bf16
        float bb = bias0[colb];
#pragma unroll
        for (int r = 0; r < 4; ++r) {
          float v = c[r] + bb;
          float gl = 0.5f * v * (1.0f + erff(v * 0.70710678118654752f));
          ((u16*)outp)[(size_t)(rowbase + r) * N + colb] = f2bf(gl);
        }
      }
    }
  }
}

//============================ split-K GEMM (8 waves, 2 K-groups, quad-buffered, XCD-chunked) ============================
// R24's validated quad-buffer counted-vmcnt loop (HBM-fed staging needs depth-2
// in flight; paired vmcnt(0) regressed in R25). NEW: linear 256-block grid with
// 2D XCD chunking — xcd owns a 4n x 8m region (unique panels ~12 MB/XCD instead
// of every panel on every XCD; same mechanism that cut gemm_256 FETCH in R13).
__global__ __launch_bounds__(512) void gemm_sk(
    const u16* __restrict__ A, const u16* __restrict__ Bt,
    const float* __restrict__ bias0, float* __restrict__ outp,
    const float* __restrict__ res, int M, int N, int K) {
  __shared__ __align__(16) union SM {
    struct { u16 As[2][4][128 * 32]; u16 Bs[2][4][128 * 32]; } t;  // [grp][buf]
    float red[16][4][4][64];
  } sm;
  const int tid = threadIdx.x;
  const int w8 = tid >> 6, lane = tid & 63;
  const int gg = w8 >> 2, wl = w8 & 3;
  // 2D XCD chunk: xcd = bid&7 -> (xcd&1) selects 4-wide n-range, (xcd>>1) selects 8-tall m-range
  const int xcd = blockIdx.x & 7, idx = blockIdx.x >> 3;
  const int bxn = (xcd & 1) * 4 + (idx & 3);   // 0..7
  const int bym = (xcd >> 1) * 8 + (idx >> 2); // 0..31
  const int m0 = bym << 7, n0 = bxn << 7;

  char* asB = (char*)sm.t.As[gg];
  char* bsB = (char*)sm.t.Bs[gg];
  const u16* aS[2];
  const u16* bS[2];
#pragma unroll
  for (int i = 0; i < 2; ++i) {
    int p = wl * 2048 + i * 1024 + lane * 16;
    int r = p >> 6;
    int cl = ((p >> 4) & 3) ^ ((r >> 1) & 3);
    aS[i] = A + (size_t)(m0 + r) * K + gg * 32 + cl * 8;
    bS[i] = Bt + (size_t)(n0 + r) * K + gg * 32 + cl * 8;
  }
  f32x4 acc[4][4];
#pragma unroll
  for (int i = 0; i < 4; ++i)
#pragma unroll
    for (int j = 0; j < 4; ++j) acc[i][j] = f32x4{0.f, 0.f, 0.f, 0.f};

  const int wr = wl >> 1, wc = wl & 1;
  int aOff[4], bOff[4];
#pragma unroll
  for (int mm = 0; mm < 4; ++mm) {
    int rowa = wr * 64 + mm * 16 + (lane & 15);
    aOff[mm] = rowa * 64 + (((lane >> 4) ^ ((rowa >> 1) & 3)) << 4);
    int rowb = wc * 64 + mm * 16 + (lane & 15);
    bOff[mm] = rowb * 64 + (((lane >> 4) ^ ((rowb >> 1) & 3)) << 4);
  }

  gl_lds16(aS[0], asB + wl * 2048);
  gl_lds16(aS[1], asB + wl * 2048 + 1024);
  gl_lds16(bS[0], bsB + wl * 2048);
  gl_lds16(bS[1], bsB + wl * 2048 + 1024);
  if (K > 64) {
    gl_lds16(aS[0] + 64, asB + 8192 + wl * 2048);
    gl_lds16(aS[1] + 64, asB + 8192 + wl * 2048 + 1024);
    gl_lds16(bS[0] + 64, bsB + 8192 + wl * 2048);
    gl_lds16(bS[1] + 64, bsB + 8192 + wl * 2048 + 1024);
  }
  if (K > 128) {
    gl_lds16(aS[0] + 128, asB + 16384 + wl * 2048);
    gl_lds16(aS[1] + 128, asB + 16384 + wl * 2048 + 1024);
    gl_lds16(bS[0] + 128, bsB + 16384 + wl * 2048);
    gl_lds16(bS[1] + 128, bsB + 16384 + wl * 2048 + 1024);
  }
  int buf = 0;
  for (int ks = 0; ks < K; ks += 64) {
    const int rem = ((K - ks) >> 6) - 1;
    if (rem >= 2)      { asm volatile("s_waitcnt vmcnt(8)" ::: "memory"); }
    else if (rem == 1) { asm volatile("s_waitcnt vmcnt(4)" ::: "memory"); }
    else               { asm volatile("s_waitcnt vmcnt(0)" ::: "memory"); }
    __builtin_amdgcn_s_barrier();
    asm volatile("" ::: "memory");
    if (ks + 192 < K) {
      const int nb = ((buf + 3) & 3) * 8192;
      gl_lds16(aS[0] + ks + 192, asB + nb + wl * 2048);
      gl_lds16(aS[1] + ks + 192, asB + nb + wl * 2048 + 1024);
      gl_lds16(bS[0] + ks + 192, bsB + nb + wl * 2048);
      gl_lds16(bS[1] + ks + 192, bsB + nb + wl * 2048 + 1024);
    }
    const int tb = buf * 8192;
    bf16x8 av[4], bv[4];
#pragma unroll
    for (int mm = 0; mm < 4; ++mm) av[mm] = *(const bf16x8*)(asB + tb + aOff[mm]);
#pragma unroll
    for (int nn = 0; nn < 4; ++nn) bv[nn] = *(const bf16x8*)(bsB + tb + bOff[nn]);
#pragma unroll
    for (int mm = 0; mm < 4; ++mm)
#pragma unroll
      for (int nn = 0; nn < 4; ++nn)
        acc[mm][nn] = __builtin_amdgcn_mfma_f32_16x16x32_bf16(av[mm], bv[nn], acc[mm][nn], 0, 0, 0);
    buf = (buf + 1) & 3;
  }

  __syncthreads();  // all tile reads done before red overwrites the union
  if (gg == 1) {
#pragma unroll
    for (int mm = 0; mm < 4; ++mm)
#pragma unroll
      for (int nn = 0; nn < 4; ++nn)
#pragma unroll
        for (int r = 0; r < 4; ++r) sm.red[mm * 4 + nn][r][wl][lane] = acc[mm][nn][r];
  }
  __syncthreads();
  if (gg == 0) {
    const int g = lane >> 4, ci = lane & 15;
#pragma unroll
    for (int mm = 0; mm < 4; ++mm) {
#pragma unroll
      for (int nn = 0; nn < 4; ++nn) {
        int colb = n0 + wc * 64 + nn * 16 + ci;
        int rowbase = m0 + wr * 64 + mm * 16 + 4 * g;
        float bb = bias0[colb];
#pragma unroll
        for (int r = 0; r < 4; ++r) {
          size_t idx2 = (size_t)(rowbase + r) * N + colb;
          outp[idx2] = acc[mm][nn][r] + sm.red[mm * 4 + nn][r][wl][lane] + bb + res[idx2];
        }
      }
    }
  }
}

//============================ flash attention (8x16 paired, 4 steps/barrier) ============================
// (unchanged from R24 — validated)
__global__ __launch_bounds__(512) void attn_k(const u16* __restrict__ Q, const u16* __restrict__ Kg,
                                              const u16* __restrict__ Vt, u16* __restrict__ O) {
  __shared__ __align__(16) u16 Ks[2][4][64 * 64];  // [phase][step]
  __shared__ __align__(16) u16 Vs[2][4][64 * 64];
  const int bx = blockIdx.y;  // 0..7
  const int bh = blockIdx.x;  // 0..31
  const int tid = threadIdx.x, w = tid >> 6, lane = tid & 63;
  const int g = lane >> 4, qi = lane & 15;
  const u16* Qb = Q + (size_t)bh * 2048 * 64;
  const u16* Kb = Kg + (size_t)bh * 2048 * 64;
  const u16* Vtb = Vt + (size_t)bh * 64 * 2048;

  const int rS = tid >> 3, cS = tid & 7;
  const int csw = (cS ^ (rS & 7)) * 8;
  const u16* srcK = Kb + (size_t)rS * 64 + csw;
  const u16* srcV = Vtb + (size_t)rS * 2048 + csw;
  char* ksB = (char*)Ks;
  char* vsB = (char*)Vs;
  const int dstOff = tid * 16;

  int koff[4][2], voff[4][2];
#pragma unroll
  for (int t = 0; t < 4; ++t) {
    int row = 16 * t + qi;
#pragma unroll
    for (int h = 0; h < 2; ++h) koff[t][h] = row * 128 + (((4 * h + g) ^ (qi & 7)) << 4);
#pragma unroll
    for (int kt = 0; kt < 2; ++kt) voff[t][kt] = row * 128 + (((4 * kt + g) ^ (qi & 7)) << 4);
  }

  const int b_ = bh >> 4, hh = bh & 15;
  u32* Ou = (u32*)O;

  for (int job = 0; job < 2; ++job) {
    const int qt = job ? bx : 15 - bx;
    const int qmin = qt * 128 + w * 16;
    const int qrow = qmin + qi;
    const int qmaxw = qmin + 15;

    bf16x8 qf[2];
#pragma unroll
    for (int h = 0; h < 2; ++h)
      qf[h] = *(const bf16x8*)(Qb + (size_t)qrow * 64 + h * 32 + g * 8);

    f32x4 acc[4];
#pragma unroll
    for (int dt = 0; dt < 4; ++dt) acc[dt] = f32x4{0.f, 0.f, 0.f, 0.f};
    float m = -1e30f, lsum = 0.0f;

    __syncthreads();  // protect LDS reuse across jobs
#pragma unroll
    for (int j = 0; j < 4; ++j) {
      gl_lds16(srcK + (size_t)j * 4096, ksB + j * 8192 + dstOff);
      gl_lds16(srcV + (size_t)j * 64, vsB + j * 8192 + dstOff);
    }

    const int nsteps = 2 * qt + 2;
    const int quads = (nsteps + 3) >> 2;
    int ph = 0;
    for (int ss = 0; ss < quads; ++ss) {
      __syncthreads();
      if (ss + 1 < quads) {
        const int nb = (ph ^ 1) * 32768;
#pragma unroll
        for (int j = 0; j < 4; ++j) {
          const int sj = 4 * ss + 4 + j;
          gl_lds16(srcK + (size_t)sj * 4096, ksB + nb + j * 8192 + dstOff);
          gl_lds16(srcV + (size_t)sj * 64, vsB + nb + j * 8192 + dstOff);
        }
      }
#pragma unroll
      for (int j = 0; j < 4; ++j) {
        const int s = 4 * ss + j;
        const int kv0 = s * 64;
        if (kv0 <= qmaxw) {
          const int tb = ph * 32768 + j * 8192;
          f32x4 st[4];
          __builtin_amdgcn_s_setprio(1);
#pragma unroll
          for (int t = 0; t < 4; ++t) {
            st[t] = f32x4{0.f, 0.f, 0.f, 0.f};
#pragma unroll
            for (int h = 0; h < 2; ++h) {
              bf16x8 kf = *(const bf16x8*)(ksB + tb + koff[t][h]);
              st[t] = __builtin_amdgcn_mfma_f32_16x16x32_bf16(kf, qf[h], st[t], 0, 0, 0);
            }
          }
          __builtin_amdgcn_s_setprio(0);
          float pvv[4][4];
          float tmax = -1e30f;
          if (kv0 + 63 > qmin) {
#pragma unroll
            for (int t = 0; t < 4; ++t)
#pragma unroll
              for (int r = 0; r < 4; ++r) {
                int key = kv0 + 16 * t + 4 * g + r;
                float sv = st[t][r];
                sv = (key <= qrow) ? sv : -1e30f;
                pvv[t][r] = sv;
                tmax = fmaxf(tmax, sv);
              }
          } else {
#pragma unroll
            for (int t = 0; t < 4; ++t)
#pragma unroll
              for (int r = 0; r < 4; ++r) {
                float sv = st[t][r];
                pvv[t][r] = sv;
                tmax = fmaxf(tmax, sv);
              }
          }
          tmax = fmaxf(tmax, __shfl_xor(tmax, 16, 64));
          tmax = fmaxf(tmax, __shfl_xor(tmax, 32, 64));
          if (!__all(tmax <= m + 8.0f)) {  // defer-max (T13)
            float mn = fmaxf(m, tmax);
            float corr = __expf(m - mn);
            lsum *= corr;
#pragma unroll
            for (int dt = 0; dt < 4; ++dt)
#pragma unroll
              for (int r = 0; r < 4; ++r) acc[dt][r] *= corr;
            m = mn;
          }
          float tsum = 0.f;
#pragma unroll
          for (int t = 0; t < 4; ++t)
#pragma unroll
            for (int r = 0; r < 4; ++r) {
              float e = __expf(pvv[t][r] - m);
              pvv[t][r] = e;
              tsum += e;
            }
          tsum += __shfl_xor(tsum, 16, 64);
          tsum += __shfl_xor(tsum, 32, 64);
          lsum += tsum;
          u32 pk[4][2], ex[4][2];
#pragma unroll
          for (int t = 0; t < 4; ++t)
#pragma unroll
            for (int p = 0; p < 2; ++p) {
              u32 v = cvtpk(pvv[t][2 * p], pvv[t][2 * p + 1]);
              pk[t][p] = v;
              ex[t][p] = (u32)__shfl_xor((int)v, 16, 64);
            }
          const bool ge = (g & 1) == 0;
          const bool G0 = (g >> 1) == 0;
          const bool innr = (g == 0) || (g == 3);
          u32 mm_[4][4];
#pragma unroll
          for (int t = 0; t < 4; ++t) {
            mm_[t][0] = ge ? pk[t][0] : ex[t][0];
            mm_[t][1] = ge ? pk[t][1] : ex[t][1];
            mm_[t][2] = ge ? ex[t][0] : pk[t][0];
            mm_[t][3] = ge ? ex[t][1] : pk[t][1];
          }
          union Frag { u32 u[4]; bf16x8 v; } f0, f1;
#pragma unroll
          for (int i = 0; i < 4; ++i) {
            u32 sel0 = G0 ? mm_[1][i] : mm_[0][i];
            u32 sel1 = G0 ? mm_[3][i] : mm_[2][i];
            u32 sw0 = (u32)__shfl_xor((int)sel0, 32, 64);
            u32 sw1 = (u32)__shfl_xor((int)sel1, 32, 64);
            u32 own0 = G0 ? mm_[0][i] : mm_[1][i];
            u32 own1 = G0 ? mm_[2][i] : mm_[3][i];
            f0.u[i] = innr ? own0 : sw0;
            f1.u[i] = innr ? own1 : sw1;
          }
          __builtin_amdgcn_s_setprio(1);
#pragma unroll
          for (int dt = 0; dt < 4; ++dt) {
            bf16x8 vfa = *(const bf16x8*)(vsB + tb + voff[dt][0]);
            acc[dt] = __builtin_amdgcn_mfma_f32_16x16x32_bf16(vfa, f0.v, acc[dt], 0, 0, 0);
            bf16x8 vfb = *(const bf16x8*)(vsB + tb + voff[dt][1]);
            acc[dt] = __builtin_amdgcn_mfma_f32_16x16x32_bf16(vfb, f1.v, acc[dt], 0, 0, 0);
          }
          __builtin_amdgcn_s_setprio(0);
        }
      }
      ph ^= 1;
    }

    float rl = 1.0f / lsum;
    size_t rowq = (size_t)(b_ * 2048 + qrow);
#pragma unroll
    for (int dt = 0; dt < 4; ++dt) {
#pragma unroll
      for (int rp = 0; rp < 2; ++rp) {
        u16 lo = f2bf(acc[dt][rp * 2] * rl);
        u16 hi = f2bf(acc[dt][rp * 2 + 1] * rl);
        u32 pkd = (u32)lo | ((u32)hi << 16);
        size_t off = rowq * 1024 + hh * 64 + dt * 16 + 4 * g + rp * 2;
        Ou[off >> 1] = pkd;
      }
    }
  }
}

//============================ launch ============================
extern "C" void kernel_launch(void* const* d_in, const int* in_sizes, int n_in,
                              void* d_out, int out_size, void* d_ws, size_t ws_size,
                              hipStream_t stream) {
  const float* x    = (const float*)d_in[0];
  const float* ln1g = (const float*)d_in[1];
  const float* ln1b = (const float*)d_in[2];
  const float* Wq   = (const float*)d_in[3];
  const float* bq   = (const float*)d_in[4];
  const float* Wk   = (const float*)d_in[5];
  const float* bk   = (const float*)d_in[6];
  const float* Wv   = (const float*)d_in[7];
  const float* bv   = (const float*)d_in[8];
  const float* Wo   = (const float*)d_in[9];
  const float* bo   = (const float*)d_in[10];
  const float* ln2g = (const float*)d_in[11];
  const float* ln2b = (const float*)d_in[12];
  const float* W1   = (const float*)d_in[13];
  const float* b1   = (const float*)d_in[14];
  const float* W2   = (const float*)d_in[15];
  const float* b2   = (const float*)d_in[16];

  char* ws = (char*)d_ws;
  const size_t MB = 1ull << 20;
  u16* WqT = (u16*)(ws + 0 * MB);   // [1024][1024]; WqT/WkT/WvT contiguous => [3072][1024]
  u16* WkT = (u16*)(ws + 2 * MB);   // [1024][1024]
  u16* WvT = (u16*)(ws + 4 * MB);   // [1024][1024]
  u16* WoT = (u16*)(ws + 6 * MB);   // [1024][1024]
  u16* W1T = (u16*)(ws + 8 * MB);   // [4096][1024]
  u16* W2T = (u16*)(ws + 16 * MB);  // [1024][4096]
  u16* XN  = (u16*)(ws + 24 * MB);  // [4096][1024] bf16 (ln1 out, later ln2 out)
  u16* Qb  = (u16*)(ws + 32 * MB);  // [B,H,T,64] bf16
  u16* Kb  = (u16*)(ws + 40 * MB);  // [B,H,T,64] bf16
  u16* Vtb = (u16*)(ws + 48 * MB);  // [B,H,64,T] bf16 (transposed)
  u16* Ob  = (u16*)(ws + 56 * MB);  // [4096][1024] bf16
  u16* Gb  = (u16*)(ws + 32 * MB);  // [4096][4096] bf16, aliases Q/K/V/O (dead by then)

  CastArgs ca;
  ca.s[0] = Wq; ca.s[1] = Wk; ca.s[2] = Wv; ca.s[3] = Wo; ca.s[4] = W1; ca.s[5] = W2;
  ca.d[0] = WqT; ca.d[1] = WkT; ca.d[2] = WvT; ca.d[3] = WoT; ca.d[4] = W1T; ca.d[5] = W2T;
  cast_w<<<12288, 256, 0, stream>>>(ca);

  ln_k<<<4096, 256, 0, stream>>>(x, ln1g, ln1b, XN);

  // fused QKV: [4096,1024] @ [1024,3072] — 256x192 tiles -> 16x16 grid = 256 blocks
  gemm_256<2, 192><<<256, 512, 0, stream>>>(XN, WqT, bq, bk, bv, Qb, 8, 4, 4, 4096, 3072, 1024);

  attn_k<<<dim3(32, 8), 512, 0, stream>>>(Qb, Kb, Vtb, Ob);

  // x1 = x + attn @ Wo + bo   (x1 lives in d_out) — split-K, XCD-chunked linear grid
  gemm_sk<<<256, 512, 0, stream>>>(Ob, WoT, bo, (float*)d_out, x, 4096, 1024, 1024);

  ln_k<<<4096, 256, 0, stream>>>((const float*)d_out, ln2g, ln2b, XN);

  // G = gelu(h @ W1 + b1) — 256x256 tiles; XCD region 8m x 4n
  gemm_256<3, 256><<<256, 512, 0, stream>>>(XN, W1T, b1, nullptr, nullptr, Gb, 8, 4, 4, 4096, 4096, 1024);

  // out = x1 + G @ W2 + b2  (in place over d_out) — split-K, XCD-chunked linear grid
  gemm_sk<<<256, 512, 0, stream>>>(Gb, W2T, b2, (float*)d_out, (const float*)d_out, 4096, 1024, 4096);
}

// Round 27
// 219.828 us; speedup vs baseline: 1.0517x; 1.0065x over previous
//
#include <hip/hip_runtime.h>
#include <hip/hip_bf16.h>

typedef __attribute__((ext_vector_type(4))) float f32x4;
typedef __attribute__((ext_vector_type(8))) short bf16x8;
typedef unsigned int u32;
typedef unsigned short u16;

#define GASP __attribute__((address_space(1)))
#define LASP __attribute__((address_space(3)))

__device__ __forceinline__ u16 f2bf(float f) {
  u32 u = __float_as_uint(f);
  return (u16)((u + 0x7fffu + ((u >> 16) & 1u)) >> 16);
}

__device__ __forceinline__ u32 cvtpk(float lo, float hi) {
  u32 r;
  asm("v_cvt_pk_bf16_f32 %0, %1, %2" : "=v"(r) : "v"(lo), "v"(hi));
  return r;
}

__device__ __forceinline__ void gl_lds16(const void* g, void* l) {
  __builtin_amdgcn_global_load_lds((const GASP u32*)g, (LASP u32*)l, 16, 0, 0);
}

//============================ weight cast + transpose ============================
// W[K][N] fp32 -> Wt[N][K] bf16
struct CastArgs {
  const float* s[6];
  u16* d[6];
};

__global__ __launch_bounds__(256) void cast_w(CastArgs a) {
  int bid = blockIdx.x;
  int w, t, K, N, kshift;
  if (bid < 4096)      { w = bid >> 10; t = bid & 1023; K = 1024; N = 1024; kshift = 5; }
  else if (bid < 8192) { w = 4; t = bid - 4096; K = 1024; N = 4096; kshift = 5; }
  else                 { w = 5; t = bid - 8192; K = 4096; N = 1024; kshift = 7; }
  int tk = t & ((1 << kshift) - 1);
  int tn = t >> kshift;
  int k0 = tk << 5, n0 = tn << 5;
  const float* src = a.s[w];
  u16* dst = a.d[w];
  __shared__ u16 tile[32][36];
  int r = threadIdx.x >> 3, c0 = (threadIdx.x & 7) << 2;
  float4 v = *(const float4*)&src[(size_t)(k0 + r) * N + n0 + c0];
  tile[c0 + 0][r] = f2bf(v.x);
  tile[c0 + 1][r] = f2bf(v.y);
  tile[c0 + 2][r] = f2bf(v.z);
  tile[c0 + 3][r] = f2bf(v.w);
  __syncthreads();
  ushort4 o;
  o.x = tile[r][c0 + 0];
  o.y = tile[r][c0 + 1];
  o.z = tile[r][c0 + 2];
  o.w = tile[r][c0 + 3];
  *(ushort4*)&dst[(size_t)(n0 + r) * K + k0 + c0] = o;
}

//============================ layernorm -> bf16 ============================
__global__ __launch_bounds__(256) void ln_k(const float* __restrict__ x, const float* __restrict__ g,
                                            const float* __restrict__ b, u16* __restrict__ out) {
  int row = blockIdx.x;
  int tid = threadIdx.x;
  float4 v = *(const float4*)&x[(size_t)row * 1024 + tid * 4];
  float s = v.x + v.y + v.z + v.w;
  float ss = v.x * v.x + v.y * v.y + v.z * v.z + v.w * v.w;
#pragma unroll
  for (int o = 32; o >= 1; o >>= 1) {
    s += __shfl_xor(s, o, 64);
    ss += __shfl_xor(ss, o, 64);
  }
  __shared__ float red[8];
  int wv = tid >> 6;
  if ((tid & 63) == 0) { red[wv] = s; red[wv + 4] = ss; }
  __syncthreads();
  s = red[0] + red[1] + red[2] + red[3];
  ss = red[4] + red[5] + red[6] + red[7];
  float mu = s * (1.0f / 1024.0f);
  float var = ss * (1.0f / 1024.0f) - mu * mu;
  float rstd = rsqrtf(var + 1e-5f);
  float4 gv = *(const float4*)&g[tid * 4];
  float4 bv = *(const float4*)&b[tid * 4];
  ushort4 o4;
  o4.x = f2bf((v.x - mu) * rstd * gv.x + bv.x);
  o4.y = f2bf((v.y - mu) * rstd * gv.y + bv.y);
  o4.z = f2bf((v.z - mu) * rstd * gv.z + bv.z);
  o4.w = f2bf((v.w - mu) * rstd * gv.w + bv.w);
  *(ushort4*)&out[(size_t)row * 1024 + tid * 4] = o4;
}

//============================ 256xBN GEMM, 1-barrier-per-tile, B tri-buffered ============================
// A double-buffered [2][256x64]; B TRIPLE-buffered [3][BNx64] (QKV 136 KB, W1 160 KB).
// Tile t (A dbuf d=t&1, B buf t%3): read A[d], B[t%3];
//   P0/P1 stage A(t+1) -> A[d^1]   (WAR: A[d^1] last read tile t-1, barrier separates)
//   P2/P3 stage B(t+2) -> B[(t+2)%3] (= B[(t-1)%3], last read tile t-1, barrier separates)
// Tile end (t+2<T): vmcnt(NN) leaves B(t+2)'s NN loads in flight; forces A(t+1)
//   (issued ~1800 cyc prior) and B(t+1) (issued last tile) complete -> drain ~0.
//   t==T-2: vmcnt(0). t==T-1: no wait (epilogue). One s_barrier per tile.
// Prologue: A(0)->A[0], B(0)->B[0], B(1)->B[1]; vmcnt(NN) floats B(1).
template <int MODE, int BN>
__global__ __launch_bounds__(512) void gemm_256(
    const u16* __restrict__ A, const u16* __restrict__ Bt,
    const float* __restrict__ bias0, const float* __restrict__ bias1, const float* __restrict__ bias2,
    void* outp, int rm, int rn, int xn, int M, int N, int K) {
  constexpr int NN = BN / 64;   // B fragments per wave / B staging loads per tile (3 or 4)
  constexpr int BB = BN * 128;  // B buf bytes
  __shared__ __align__(16) u16 As[2][256 * 64];
  __shared__ __align__(16) u16 Bs[3][BN * 64];
  char* asB = (char*)As;
  char* bsB = (char*)Bs;
  const int tid = threadIdx.x;
  const int w = tid >> 6, lane = tid & 63;
  const int xcd = blockIdx.x & 7, idx = blockIdx.x >> 3;
  const int mt = (xcd / xn) * rm + (idx % rm);
  const int nt = (xcd % xn) * rn + (idx / rm);
  const int m0 = mt << 8, n0 = nt * BN;

  const int rA = tid >> 3;                       // row within 64-row pass
  const int csw = ((tid & 7) ^ (rA & 7)) * 8;    // pre-swizzled source chunk
  const u16* pA = A + (size_t)(m0 + rA) * K + csw;
  const u16* pB = Bt + (size_t)(n0 + rA) * K + csw;
  const int dstOff = tid * 16;

#define STG_A(kt, j) gl_lds16(pA + (size_t)((j) * 64) * K + (size_t)(kt) * 64, asB + aNB + (j) * 8192 + dstOff)
#define STG_B(kt, j) gl_lds16(pB + (size_t)((j) * 64) * K + (size_t)(kt) * 64, bsB + bNB + (j) * 8192 + dstOff)

  const int wr = w >> 2, wc = w & 3;
  const int g = lane >> 4, qi = lane & 15;

  int aOff[8][2], bOff[NN][2];
#pragma unroll
  for (int mm = 0; mm < 8; ++mm) {
    int row = wr * 128 + mm * 16 + qi;
#pragma unroll
    for (int ks = 0; ks < 2; ++ks)
      aOff[mm][ks] = row * 128 + (((ks * 4 + g) ^ (qi & 7)) << 4);
  }
#pragma unroll
  for (int nn = 0; nn < NN; ++nn) {
    int rowb = wc * (BN / 4) + nn * 16 + qi;
#pragma unroll
    for (int ks = 0; ks < 2; ++ks)
      bOff[nn][ks] = rowb * 128 + (((ks * 4 + g) ^ (qi & 7)) << 4);
  }

  f32x4 acc[8][NN];
#pragma unroll
  for (int i = 0; i < 8; ++i)
#pragma unroll
    for (int j = 0; j < NN; ++j) acc[i][j] = f32x4{0.f, 0.f, 0.f, 0.f};

#define PAIR(MB, A00, A01, A10, A11) do {                                                \
    __builtin_amdgcn_s_setprio(1);                                                       \
    _Pragma("unroll")                                                                    \
    for (int nn = 0; nn < NN; ++nn) {                                                    \
      acc[(MB)][nn] = __builtin_amdgcn_mfma_f32_16x16x32_bf16(A00, bv[nn][0], acc[(MB)][nn], 0, 0, 0);         \
      acc[(MB) + 1][nn] = __builtin_amdgcn_mfma_f32_16x16x32_bf16(A10, bv[nn][0], acc[(MB) + 1][nn], 0, 0, 0); \
    }                                                                                    \
    _Pragma("unroll")                                                                    \
    for (int nn = 0; nn < NN; ++nn) {                                                    \
      acc[(MB)][nn] = __builtin_amdgcn_mfma_f32_16x16x32_bf16(A01, bv[nn][1], acc[(MB)][nn], 0, 0, 0);         \
      acc[(MB) + 1][nn] = __builtin_amdgcn_mfma_f32_16x16x32_bf16(A11, bv[nn][1], acc[(MB) + 1][nn], 0, 0, 0); \
    }                                                                                    \
    __builtin_amdgcn_s_setprio(0);                                                       \
  } while (0)

#define RDA(dst0, dst1, MB)                                          \
    bf16x8 dst0##0 = *(const bf16x8*)(asB + aTB + aOff[(MB)][0]);     \
    bf16x8 dst0##1 = *(const bf16x8*)(asB + aTB + aOff[(MB)][1]);     \
    bf16x8 dst1##0 = *(const bf16x8*)(asB + aTB + aOff[(MB) + 1][0]); \
    bf16x8 dst1##1 = *(const bf16x8*)(asB + aTB + aOff[(MB) + 1][1]);

#define WAIT_NN() do {                                              \
    if constexpr (NN == 3) { asm volatile("s_waitcnt vmcnt(3)" ::: "memory"); } \
    else                   { asm volatile("s_waitcnt vmcnt(4)" ::: "memory"); } \
  } while (0)

  const int T = K >> 6;
  // prologue: A(0)->A[0], B(0)->B[0], B(1)->B[1]
#pragma unroll
  for (int j = 0; j < 4; ++j) gl_lds16(pA + (size_t)(j * 64) * K, asB + j * 8192 + dstOff);
#pragma unroll
  for (int j = 0; j < NN; ++j) gl_lds16(pB + (size_t)(j * 64) * K, bsB + j * 8192 + dstOff);
  if (T > 1) {
#pragma unroll
    for (int j = 0; j < NN; ++j) gl_lds16(pB + (size_t)(j * 64) * K + 64, bsB + BB + j * 8192 + dstOff);
    WAIT_NN();  // floats B(1); forces A(0), B(0)
  } else {
    asm volatile("s_waitcnt vmcnt(0)" ::: "memory");
  }
  __builtin_amdgcn_s_barrier();

  for (int t = 0; t < T; ++t) {
    const int d = t & 1;
    const int aTB = d * 32768;
    const int bTB = (t % 3) * BB;
    const int aNB = (d ^ 1) * 32768;
    const int bNB = ((t + 2) % 3) * BB;
    const bool moreA = (t + 1 < T);
    const bool moreB = (t + 2 < T);
    const int kt1 = t + 1, kt2 = t + 2;
    bf16x8 bv[NN][2];
#pragma unroll
    for (int nn = 0; nn < NN; ++nn) {
      bv[nn][0] = *(const bf16x8*)(bsB + bTB + bOff[nn][0]);
      bv[nn][1] = *(const bf16x8*)(bsB + bTB + bOff[nn][1]);
    }
    RDA(p0a, p0b, 0);
    if (moreA) { STG_A(kt1, 0); STG_A(kt1, 1); }
    PAIR(0, p0a0, p0a1, p0b0, p0b1);
    RDA(p1a, p1b, 2);
    if (moreA) { STG_A(kt1, 2); STG_A(kt1, 3); }
    PAIR(2, p1a0, p1a1, p1b0, p1b1);
    RDA(p2a, p2b, 4);
    if (moreB) { STG_B(kt2, 0); STG_B(kt2, 1); }
    PAIR(4, p2a0, p2a1, p2b0, p2b1);
    RDA(p3a, p3b, 6);
    if (moreB) {
#pragma unroll
      for (int j = 2; j < NN; ++j) STG_B(kt2, j);
    }
    PAIR(6, p3a0, p3a1, p3b0, p3b1);
    asm volatile("" ::: "memory");
    if (moreB)      { WAIT_NN(); }   // float B(t+2); force A(t+1), B(t+1)
    else if (moreA) { asm volatile("s_waitcnt vmcnt(0)" ::: "memory"); }
    __builtin_amdgcn_s_barrier();
  }
#undef PAIR
#undef RDA
#undef STG_A
#undef STG_B
#undef WAIT_NN

  const int ci = lane & 15;
#pragma unroll
  for (int mm = 0; mm < 8; ++mm) {
#pragma unroll
    for (int nn = 0; nn < NN; ++nn) {
      int colb = n0 + wc * (BN / 4) + nn * 16 + ci;
      int rowbase = m0 + wr * 128 + mm * 16 + 4 * g;
      f32x4 c = acc[mm][nn];
      if constexpr (MODE == 2) {
        int sel = colb >> 10;
        int cc = colb & 1023;
        const float* bp = sel == 0 ? bias0 : (sel == 1 ? bias1 : bias2);
        float bb = bp[cc];
        int h = cc >> 6, dd = cc & 63;
        int b_ = rowbase >> 11, tt = rowbase & 2047;
        if (sel == 2) {
          // V^T: [B,H,64,T]; 4 consecutive t per lane -> vector store
          u16* op = (u16*)outp + 2ull * (4096ull * 1024ull);
          ushort4 o4;
          o4.x = f2bf(c[0] + bb);
          o4.y = f2bf(c[1] + bb);
          o4.z = f2bf(c[2] + bb);
          o4.w = f2bf(c[3] + bb);
          *(ushort4*)&op[((size_t)(b_ * 16 + h) * 64 + dd) * 2048 + tt] = o4;
        } else {
          float scale = (sel == 0) ? 0.125f : 1.0f;
          u16* op = (u16*)outp + (size_t)sel * (4096ull * 1024ull);
#pragma unroll
          for (int r = 0; r < 4; ++r)
            op[((size_t)(b_ * 16 + h) * 2048 + tt + r) * 64 + dd] = f2bf((c[r] + bb) * scale);
        }
      } else {  // MODE 3: gelu -> bf16
        float bb = bias0[colb];
#pragma unroll
        for (int r = 0; r < 4; ++r) {
          float v = c[r] + bb;
          float gl = 0.5f * v * (1.0f + erff(v * 0.70710678118654752f));
          ((u16*)outp)[(size_t)(rowbase + r) * N + colb] = f2bf(gl);
        }
      }
    }
  }
}

//============================ split-K GEMM (8 waves, 2 K-groups, quad-buffered, XCD-chunked) ============================
// (unchanged from R26 — validated)
__global__ __launch_bounds__(512) void gemm_sk(
    const u16* __restrict__ A, const u16* __restrict__ Bt,
    const float* __restrict__ bias0, float* __restrict__ outp,
    const float* __restrict__ res, int M, int N, int K) {
  __shared__ __align__(16) union SM {
    struct { u16 As[2][4][128 * 32]; u16 Bs[2][4][128 * 32]; } t;  // [grp][buf]
    float red[16][4][4][64];
  } sm;
  const int tid = threadIdx.x;
  const int w8 = tid >> 6, lane = tid & 63;
  const int gg = w8 >> 2, wl = w8 & 3;
  const int xcd = blockIdx.x & 7, idx = blockIdx.x >> 3;
  const int bxn = (xcd & 1) * 4 + (idx & 3);   // 0..7
  const int bym = (xcd >> 1) * 8 + (idx >> 2); // 0..31
  const int m0 = bym << 7, n0 = bxn << 7;

  char* asB = (char*)sm.t.As[gg];
  char* bsB = (char*)sm.t.Bs[gg];
  const u16* aS[2];
  const u16* bS[2];
#pragma unroll
  for (int i = 0; i < 2; ++i) {
    int p = wl * 2048 + i * 1024 + lane * 16;
    int r = p >> 6;
    int cl = ((p >> 4) & 3) ^ ((r >> 1) & 3);
    aS[i] = A + (size_t)(m0 + r) * K + gg * 32 + cl * 8;
    bS[i] = Bt + (size_t)(n0 + r) * K + gg * 32 + cl * 8;
  }
  f32x4 acc[4][4];
#pragma unroll
  for (int i = 0; i < 4; ++i)
#pragma unroll
    for (int j = 0; j < 4; ++j) acc[i][j] = f32x4{0.f, 0.f, 0.f, 0.f};

  const int wr = wl >> 1, wc = wl & 1;
  int aOff[4], bOff[4];
#pragma unroll
  for (int mm = 0; mm < 4; ++mm) {
    int rowa = wr * 64 + mm * 16 + (lane & 15);
    aOff[mm] = rowa * 64 + (((lane >> 4) ^ ((rowa >> 1) & 3)) << 4);
    int rowb = wc * 64 + mm * 16 + (lane & 15);
    bOff[mm] = rowb * 64 + (((lane >> 4) ^ ((rowb >> 1) & 3)) << 4);
  }

  gl_lds16(aS[0], asB + wl * 2048);
  gl_lds16(aS[1], asB + wl * 2048 + 1024);
  gl_lds16(bS[0], bsB + wl * 2048);
  gl_lds16(bS[1], bsB + wl * 2048 + 1024);
  if (K > 64) {
    gl_lds16(aS[0] + 64, asB + 8192 + wl * 2048);
    gl_lds16(aS[1] + 64, asB + 8192 + wl * 2048 + 1024);
    gl_lds16(bS[0] + 64, bsB + 8192 + wl * 2048);
    gl_lds16(bS[1] + 64, bsB + 8192 + wl * 2048 + 1024);
  }
  if (K > 128) {
    gl_lds16(aS[0] + 128, asB + 16384 + wl * 2048);
    gl_lds16(aS[1] + 128, asB + 16384 + wl * 2048 + 1024);
    gl_lds16(bS[0] + 128, bsB + 16384 + wl * 2048);
    gl_lds16(bS[1] + 128, bsB + 16384 + wl * 2048 + 1024);
  }
  int buf = 0;
  for (int ks = 0; ks < K; ks += 64) {
    const int rem = ((K - ks) >> 6) - 1;
    if (rem >= 2)      { asm volatile("s_waitcnt vmcnt(8)" ::: "memory"); }
    else if (rem == 1) { asm volatile("s_waitcnt vmcnt(4)" ::: "memory"); }
    else               { asm volatile("s_waitcnt vmcnt(0)" ::: "memory"); }
    __builtin_amdgcn_s_barrier();
    asm volatile("" ::: "memory");
    if (ks + 192 < K) {
      const int nb = ((buf + 3) & 3) * 8192;
      gl_lds16(aS[0] + ks + 192, asB + nb + wl * 2048);
      gl_lds16(aS[1] + ks + 192, asB + nb + wl * 2048 + 1024);
      gl_lds16(bS[0] + ks + 192, bsB + nb + wl * 2048);
      gl_lds16(bS[1] + ks + 192, bsB + nb + wl * 2048 + 1024);
    }
    const int tb = buf * 8192;
    bf16x8 av[4], bv[4];
#pragma unroll
    for (int mm = 0; mm < 4; ++mm) av[mm] = *(const bf16x8*)(asB + tb + aOff[mm]);
#pragma unroll
    for (int nn = 0; nn < 4; ++nn) bv[nn] = *(const bf16x8*)(bsB + tb + bOff[nn]);
#pragma unroll
    for (int mm = 0; mm < 4; ++mm)
#pragma unroll
      for (int nn = 0; nn < 4; ++nn)
        acc[mm][nn] = __builtin_amdgcn_mfma_f32_16x16x32_bf16(av[mm], bv[nn], acc[mm][nn], 0, 0, 0);
    buf = (buf + 1) & 3;
  }

  __syncthreads();  // all tile reads done before red overwrites the union
  if (gg == 1) {
#pragma unroll
    for (int mm = 0; mm < 4; ++mm)
#pragma unroll
      for (int nn = 0; nn < 4; ++nn)
#pragma unroll
        for (int r = 0; r < 4; ++r) sm.red[mm * 4 + nn][r][wl][lane] = acc[mm][nn][r];
  }
  __syncthreads();
  if (gg == 0) {
    const int g = lane >> 4, ci = lane & 15;
#pragma unroll
    for (int mm = 0; mm < 4; ++mm) {
#pragma unroll
      for (int nn = 0; nn < 4; ++nn) {
        int colb = n0 + wc * 64 + nn * 16 + ci;
        int rowbase = m0 + wr * 64 + mm * 16 + 4 * g;
        float bb = bias0[colb];
#pragma unroll
        for (int r = 0; r < 4; ++r) {
          size_t idx2 = (size_t)(rowbase + r) * N + colb;
          outp[idx2] = acc[mm][nn][r] + sm.red[mm * 4 + nn][r][wl][lane] + bb + res[idx2];
        }
      }
    }
  }
}

//============================ flash attention (8x16 paired, 4 steps/barrier) ============================
// (unchanged from R26 — validated)
__global__ __launch_bounds__(512) void attn_k(const u16* __restrict__ Q, const u16* __restrict__ Kg,
                                              const u16* __restrict__ Vt, u16* __restrict__ O) {
  __shared__ __align__(16) u16 Ks[2][4][64 * 64];  // [phase][step]
  __shared__ __align__(16) u16 Vs[2][4][64 * 64];
  const int bx = blockIdx.y;  // 0..7
  const int bh = blockIdx.x;  // 0..31
  const int tid = threadIdx.x, w = tid >> 6, lane = tid & 63;
  const int g = lane >> 4, qi = lane & 15;
  const u16* Qb = Q + (size_t)bh * 2048 * 64;
  const u16* Kb = Kg + (size_t)bh * 2048 * 64;
  const u16* Vtb = Vt + (size_t)bh * 64 * 2048;

  const int rS = tid >> 3, cS = tid & 7;
  const int csw = (cS ^ (rS & 7)) * 8;
  const u16* srcK = Kb + (size_t)rS * 64 + csw;
  const u16* srcV = Vtb + (size_t)rS * 2048 + csw;
  char* ksB = (char*)Ks;
  char* vsB = (char*)Vs;
  const int dstOff = tid * 16;

  int koff[4][2], voff[4][2];
#pragma unroll
  for (int t = 0; t < 4; ++t) {
    int row = 16 * t + qi;
#pragma unroll
    for (int h = 0; h < 2; ++h) koff[t][h] = row * 128 + (((4 * h + g) ^ (qi & 7)) << 4);
#pragma unroll
    for (int kt = 0; kt < 2; ++kt) voff[t][kt] = row * 128 + (((4 * kt + g) ^ (qi & 7)) << 4);
  }

  const int b_ = bh >> 4, hh = bh & 15;
  u32* Ou = (u32*)O;

  for (int job = 0; job < 2; ++job) {
    const int qt = job ? bx : 15 - bx;
    const int qmin = qt * 128 + w * 16;
    const int qrow = qmin + qi;
    const int qmaxw = qmin + 15;

    bf16x8 qf[2];
#pragma unroll
    for (int h = 0; h < 2; ++h)
      qf[h] = *(const bf16x8*)(Qb + (size_t)qrow * 64 + h * 32 + g * 8);

    f32x4 acc[4];
#pragma unroll
    for (int dt = 0; dt < 4; ++dt) acc[dt] = f32x4{0.f, 0.f, 0.f, 0.f};
    float m = -1e30f, lsum = 0.0f;

    __syncthreads();  // protect LDS reuse across jobs
#pragma unroll
    for (int j = 0; j < 4; ++j) {
      gl_lds16(srcK + (size_t)j * 4096, ksB + j * 8192 + dstOff);
      gl_lds16(srcV + (size_t)j * 64, vsB + j * 8192 + dstOff);
    }

    const int nsteps = 2 * qt + 2;
    const int quads = (nsteps + 3) >> 2;
    int ph = 0;
    for (int ss = 0; ss < quads; ++ss) {
      __syncthreads();
      if (ss + 1 < quads) {
        const int nb = (ph ^ 1) * 32768;
#pragma unroll
        for (int j = 0; j < 4; ++j) {
          const int sj = 4 * ss + 4 + j;
          gl_lds16(srcK + (size_t)sj * 4096, ksB + nb + j * 8192 + dstOff);
          gl_lds16(srcV + (size_t)sj * 64, vsB + nb + j * 8192 + dstOff);
        }
      }
#pragma unroll
      for (int j = 0; j < 4; ++j) {
        const int s = 4 * ss + j;
        const int kv0 = s * 64;
        if (kv0 <= qmaxw) {
          const int tb = ph * 32768 + j * 8192;
          f32x4 st[4];
          __builtin_amdgcn_s_setprio(1);
#pragma unroll
          for (int t = 0; t < 4; ++t) {
            st[t] = f32x4{0.f, 0.f, 0.f, 0.f};
#pragma unroll
            for (int h = 0; h < 2; ++h) {
              bf16x8 kf = *(const bf16x8*)(ksB + tb + koff[t][h]);
              st[t] = __builtin_amdgcn_mfma_f32_16x16x32_bf16(kf, qf[h], st[t], 0, 0, 0);
            }
          }
          __builtin_amdgcn_s_setprio(0);
          float pvv[4][4];
          float tmax = -1e30f;
          if (kv0 + 63 > qmin) {
#pragma unroll
            for (int t = 0; t < 4; ++t)
#pragma unroll
              for (int r = 0; r < 4; ++r) {
                int key = kv0 + 16 * t + 4 * g + r;
                float sv = st[t][r];
                sv = (key <= qrow) ? sv : -1e30f;
                pvv[t][r] = sv;
                tmax = fmaxf(tmax, sv);
              }
          } else {
#pragma unroll
            for (int t = 0; t < 4; ++t)
#pragma unroll
              for (int r = 0; r < 4; ++r) {
                float sv = st[t][r];
                pvv[t][r] = sv;
                tmax = fmaxf(tmax, sv);
              }
          }
          tmax = fmaxf(tmax, __shfl_xor(tmax, 16, 64));
          tmax = fmaxf(tmax, __shfl_xor(tmax, 32, 64));
          if (!__all(tmax <= m + 8.0f)) {  // defer-max (T13)
            float mn = fmaxf(m, tmax);
            float corr = __expf(m - mn);
            lsum *= corr;
#pragma unroll
            for (int dt = 0; dt < 4; ++dt)
#pragma unroll
              for (int r = 0; r < 4; ++r) acc[dt][r] *= corr;
            m = mn;
          }
          float tsum = 0.f;
#pragma unroll
          for (int t = 0; t < 4; ++t)
#pragma unroll
            for (int r = 0; r < 4; ++r) {
              float e = __expf(pvv[t][r] - m);
              pvv[t][r] = e;
              tsum += e;
            }
          tsum += __shfl_xor(tsum, 16, 64);
          tsum += __shfl_xor(tsum, 32, 64);
          lsum += tsum;
          u32 pk[4][2], ex[4][2];
#pragma unroll
          for (int t = 0; t < 4; ++t)
#pragma unroll
            for (int p = 0; p < 2; ++p) {
              u32 v = cvtpk(pvv[t][2 * p], pvv[t][2 * p + 1]);
              pk[t][p] = v;
              ex[t][p] = (u32)__shfl_xor((int)v, 16, 64);
            }
          const bool ge = (g & 1) == 0;
          const bool G0 = (g >> 1) == 0;
          const bool innr = (g == 0) || (g == 3);
          u32 mm_[4][4];
#pragma unroll
          for (int t = 0; t < 4; ++t) {
            mm_[t][0] = ge ? pk[t][0] : ex[t][0];
            mm_[t][1] = ge ? pk[t][1] : ex[t][1];
            mm_[t][2] = ge ? ex[t][0] : pk[t][0];
            mm_[t][3] = ge ? ex[t][1] : pk[t][1];
          }
          union Frag { u32 u[4]; bf16x8 v; } f0, f1;
#pragma unroll
          for (int i = 0; i < 4; ++i) {
            u32 sel0 = G0 ? mm_[1][i] : mm_[0][i];
            u32 sel1 = G0 ? mm_[3][i] : mm_[2][i];
            u32 sw0 = (u32)__shfl_xor((int)sel0, 32, 64);
            u32 sw1 = (u32)__shfl_xor((int)sel1, 32, 64);
            u32 own0 = G0 ? mm_[0][i] : mm_[1][i];
            u32 own1 = G0 ? mm_[2][i] : mm_[3][i];
            f0.u[i] = innr ? own0 : sw0;
            f1.u[i] = innr ? own1 : sw1;
          }
          __builtin_amdgcn_s_setprio(1);
#pragma unroll
          for (int dt = 0; dt < 4; ++dt) {
            bf16x8 vfa = *(const bf16x8*)(vsB + tb + voff[dt][0]);
            acc[dt] = __builtin_amdgcn_mfma_f32_16x16x32_bf16(vfa, f0.v, acc[dt], 0, 0, 0);
            bf16x8 vfb = *(const bf16x8*)(vsB + tb + voff[dt][1]);
            acc[dt] = __builtin_amdgcn_mfma_f32_16x16x32_bf16(vfb, f1.v, acc[dt], 0, 0, 0);
          }
          __builtin_amdgcn_s_setprio(0);
        }
      }
      ph ^= 1;
    }

    float rl = 1.0f / lsum;
    size_t rowq = (size_t)(b_ * 2048 + qrow);
#pragma unroll
    for (int dt = 0; dt < 4; ++dt) {
#pragma unroll
      for (int rp = 0; rp < 2; ++rp) {
        u16 lo = f2bf(acc[dt][rp * 2] * rl);
        u16 hi = f2bf(acc[dt][rp * 2 + 1] * rl);
        u32 pkd = (u32)lo | ((u32)hi << 16);
        size_t off = rowq * 1024 + hh * 64 + dt * 16 + 4 * g + rp * 2;
        Ou[off >> 1] = pkd;
      }
    }
  }
}

//============================ launch ============================
extern "C" void kernel_launch(void* const* d_in, const int* in_sizes, int n_in,
                              void* d_out, int out_size, void* d_ws, size_t ws_size,
                              hipStream_t stream) {
  const float* x    = (const float*)d_in[0];
  const float* ln1g = (const float*)d_in[1];
  const float* ln1b = (const float*)d_in[2];
  const float* Wq   = (const float*)d_in[3];
  const float* bq   = (const float*)d_in[4];
  const float* Wk   = (const float*)d_in[5];
  const float* bk   = (const float*)d_in[6];
  const float* Wv   = (const float*)d_in[7];
  const float* bv   = (const float*)d_in[8];
  const float* Wo   = (const float*)d_in[9];
  const float* bo   = (const float*)d_in[10];
  const float* ln2g = (const float*)d_in[11];
  const float* ln2b = (const float*)d_in[12];
  const float* W1   = (const float*)d_in[13];
  const float* b1   = (const float*)d_in[14];
  const float* W2   = (const float*)d_in[15];
  const float* b2   = (const float*)d_in[16];

  char* ws = (char*)d_ws;
  const size_t MB = 1ull << 20;
  u16* WqT = (u16*)(ws + 0 * MB);   // [1024][1024]; WqT/WkT/WvT contiguous => [3072][1024]
  u16* WkT = (u16*)(ws + 2 * MB);   // [1024][1024]
  u16* WvT = (u16*)(ws + 4 * MB);   // [1024][1024]
  u16* WoT = (u16*)(ws + 6 * MB);   // [1024][1024]
  u16* W1T = (u16*)(ws + 8 * MB);   // [4096][1024]
  u16* W2T = (u16*)(ws + 16 * MB);  // [1024][4096]
  u16* XN  = (u16*)(ws + 24 * MB);  // [4096][1024] bf16 (ln1 out, later ln2 out)
  u16* Qb  = (u16*)(ws + 32 * MB);  // [B,H,T,64] bf16
  u16* Kb  = (u16*)(ws + 40 * MB);  // [B,H,T,64] bf16
  u16* Vtb = (u16*)(ws + 48 * MB);  // [B,H,64,T] bf16 (transposed)
  u16* Ob  = (u16*)(ws + 56 * MB);  // [4096][1024] bf16
  u16* Gb  = (u16*)(ws + 32 * MB);  // [4096][4096] bf16, aliases Q/K/V/O (dead by then)

  CastArgs ca;
  ca.s[0] = Wq; ca.s[1] = Wk; ca.s[2] = Wv; ca.s[3] = Wo; ca.s[4] = W1; ca.s[5] = W2;
  ca.d[0] = WqT; ca.d[1] = WkT; ca.d[2] = WvT; ca.d[3] = WoT; ca.d[4] = W1T; ca.d[5] = W2T;
  cast_w<<<12288, 256, 0, stream>>>(ca);

  ln_k<<<4096, 256, 0, stream>>>(x, ln1g, ln1b, XN);

  // fused QKV: [4096,1024] @ [1024,3072] — 256x192 tiles -> 16x16 grid = 256 blocks
  gemm_256<2, 192><<<256, 512, 0, stream>>>(XN, WqT, bq, bk, bv, Qb, 8, 4, 4, 4096, 3072, 1024);

  attn_k<<<dim3(32, 8), 512, 0, stream>>>(Qb, Kb, Vtb, Ob);

  // x1 = x + attn @ Wo + bo   (x1 lives in d_out) — split-K, XCD-chunked linear grid
  gemm_sk<<<256, 512, 0, stream>>>(Ob, WoT, bo, (float*)d_out, x, 4096, 1024, 1024);

  ln_k<<<4096, 256, 0, stream>>>((const float*)d_out, ln2g, ln2b, XN);

  // G = gelu(h @ W1 + b1) — 256x256 tiles; XCD region 8m x 4n
  gemm_256<3, 256><<<256, 512, 0, stream>>>(XN, W1T, b1, nullptr, nullptr, Gb, 8, 4, 4, 4096, 4096, 1024);

  // out = x1 + G @ W2 + b2  (in place over d_out) — split-K, XCD-chunked linear grid
  gemm_sk<<<256, 512, 0, stream>>>(Gb, W2T, b2, (float*)d_out, (const float*)d_out, 4096, 1024, 4096);
}